// Round 9
// baseline (99.282 us; speedup 1.0000x reference)
//
#include <hip/hip_runtime.h>
#include <hip/hip_bf16.h>

#define N_ROWS 8192
#define DIM    128
#define NCHUNK 32                  // column chunks in sim kernel
#define CHUNKC (N_ROWS / NCHUNK)   // 256 cols per chunk
#define NTILE  (CHUNKC / 32)       // 8 tiles of 32 cols per chunk

// sqrt(2*log2(e)) : (s*a)·(s*b) = 2*log2(e)*a·b, so exp2(dot) = exp(2*sim)
#define ENSCALE 1.6986436f

typedef __attribute__((ext_vector_type(8)))  short short8;
typedef __attribute__((ext_vector_type(16))) float f32x16;

__device__ inline unsigned short f2bf(float f) {
    unsigned u = __float_as_uint(f);
    unsigned r = (u + 0x7FFFu + ((u >> 16) & 1u)) >> 16;
    return (unsigned short)r;
}
__device__ inline float bf2f(unsigned short u) {
    return __uint_as_float(((unsigned)u) << 16);
}
__device__ inline int labof(int4 v, int j) {
    return j == 0 ? v.x : j == 1 ? v.y : j == 2 ? v.z : v.w;
}

// Kernel 1: per-row L2 normalize embed -> bf16 (scaled by ENSCALE), and
// e2p[i] = exp(2*dot(en,pn)) in fp32.
__global__ __launch_bounds__(256) void norm_kernel(
    const float* __restrict__ embed, const float* __restrict__ proxy,
    short* __restrict__ enb, float* __restrict__ e2p)
{
    int wave = threadIdx.x >> 6, lane = threadIdx.x & 63;
    int row = blockIdx.x * 4 + wave;

    const float2 ev = *(const float2*)(embed + row * DIM + lane * 2);
    float ss = ev.x * ev.x + ev.y * ev.y;
#pragma unroll
    for (int m = 1; m < 64; m <<= 1) ss += __shfl_xor(ss, m, 64);
    float inv_e = 1.0f / fmaxf(sqrtf(ss), 1e-8f);
    float ex = ev.x * inv_e, ey = ev.y * inv_e;

    const float2 pv = *(const float2*)(proxy + row * DIM + lane * 2);
    float ps = pv.x * pv.x + pv.y * pv.y;
#pragma unroll
    for (int m = 1; m < 64; m <<= 1) ps += __shfl_xor(ps, m, 64);
    float inv_p = 1.0f / fmaxf(sqrtf(ps), 1e-8f);

    float dot = ex * (pv.x * inv_p) + ey * (pv.y * inv_p);
#pragma unroll
    for (int m = 1; m < 64; m <<= 1) dot += __shfl_xor(dot, m, 64);

    ushort2 st; st.x = f2bf(ex * ENSCALE); st.y = f2bf(ey * ENSCALE);
    *(ushort2*)(enb + row * DIM + lane * 2) = st;
    if (lane == 0) e2p[row] = __expf(2.0f * dot);
}

// Kernel 2: fused sim-GEMM + exp + full row sum (tot only; pos separate).
// NO LDS, NO barriers: direct per-wave B-fragment loads (R2-proven 98% L2
// hit path: same addresses shared by 4 waves/block and 32 blocks/chunk ->
// each line read ~16x per XCD, continuously over the kernel). ILP fix vs
// R2: wave owns 64 rows (rres0/rres1), so each 8-load tile feeds 16 MFMAs
// in TWO independent accumulator chains. Waves slip freely (no sync);
// compiler pipelines the independent loads under the MFMA chains.
// Operand-swapped MFMA: lane cl owns output rows wrbase+cl / wrbase+32+cl;
// acc regs span tile cols: col(reg) = (reg&3) + 4*hi + 8*(reg>>2).
__global__ __launch_bounds__(256, 4) void simsum_kernel(
    const short* __restrict__ enb, float* __restrict__ ptot)
{
    const int tid = threadIdx.x;
    const int wave = tid >> 6;
    const int lane = tid & 63;
    const int cl = lane & 31;       // output row lane / tile col selector
    const int hi = lane >> 5;       // k-group
    const int wrbase = blockIdx.x * 256 + wave * 64;
    const int cbase0 = blockIdx.y * CHUNKC;

    // register-resident A: the wave's 64 rows, two 32-row groups
    short8 rres0[8], rres1[8];
    {
        const short* a0 = enb + (size_t)(wrbase + cl) * DIM + hi * 8;
        const short* a1 = enb + (size_t)(wrbase + 32 + cl) * DIM + hi * 8;
#pragma unroll
        for (int kk = 0; kk < 8; kk++) {
            rres0[kk] = *(const short8*)(a0 + kk * 16);
            rres1[kk] = *(const short8*)(a1 + kk * 16);
        }
    }

    float tot0[4] = {0.f, 0.f, 0.f, 0.f};
    float tot1[4] = {0.f, 0.f, 0.f, 0.f};

#pragma unroll 2
    for (int t = 0; t < NTILE; t++) {
        const int cb = cbase0 + t * 32;

        // B fragments: lane holds B[k = kk*16 + hi*8 + j][cb + cl]
        const short* brow = enb + (size_t)(cb + cl) * DIM + hi * 8;
        short8 b[8];
#pragma unroll
        for (int kk = 0; kk < 8; kk++)
            b[kk] = *(const short8*)(brow + kk * 16);

        f32x16 c0 = {}, c1 = {};
#pragma unroll
        for (int kk = 0; kk < 8; kk++) {
            c0 = __builtin_amdgcn_mfma_f32_32x32x16_bf16(b[kk], rres0[kk], c0, 0, 0, 0);
            c1 = __builtin_amdgcn_mfma_f32_32x32x16_bf16(b[kk], rres1[kk], c1, 0, 0, 0);
        }

        const bool d0_ = (cb == wrbase);
        const bool d1_ = (cb == wrbase + 32);
#pragma unroll
        for (int r = 0; r < 16; r++) {
            int colr = (r & 3) + 4 * hi + 8 * (r >> 2);
            float s0 = __builtin_amdgcn_exp2f(c0[r]);
            float s1 = __builtin_amdgcn_exp2f(c1[r]);
            s0 = (d0_ && colr == cl) ? 0.f : s0;
            s1 = (d1_ && colr == cl) ? 0.f : s1;
            tot0[r & 3] += s0;
            tot1[r & 3] += s1;
        }
    }

    float t0 = tot0[0] + tot0[1] + tot0[2] + tot0[3];
    float t1 = tot1[0] + tot1[1] + tot1[2] + tot1[3];
    t0 += __shfl_xor(t0, 32, 64);   // merge the two k-groups (disjoint cols)
    t1 += __shfl_xor(t1, 32, 64);
    if (hi == 0) {
        ptot[blockIdx.y * N_ROWS + wrbase + cl] = t0;
        ptot[blockIdx.y * N_ROWS + wrbase + 32 + cl] = t1;
    }
}

// Kernel 3: positives + per-row loss, fused. One wave per row: int4
// ballot-scan labels, lane-parallel dot per same-label j, accumulate
// exp2; then the row's log-ratio (ptot partials read LANE-PARALLEL);
// block partial (4 rows) -> pl.
__global__ __launch_bounds__(256) void posloss_kernel(
    const short* __restrict__ enb, const int* __restrict__ label,
    const float* __restrict__ e2p, const float* __restrict__ ptot,
    float* __restrict__ pl)
{
    int wave = threadIdx.x >> 6, lane = threadIdx.x & 63;
    int row = blockIdx.x * 4 + wave;
    int mylab = label[row];

    ushort2 e2 = *(const ushort2*)(enb + (size_t)row * DIM + lane * 2);
    float ei0 = bf2f(e2.x), ei1 = bf2f(e2.y);

    // parallel partial-sum read (32 lanes, one per chunk)
    float tp = (lane < NCHUNK) ? ptot[lane * N_ROWS + row] : 0.f;

    float acc = 0.f;
#pragma unroll 1
    for (int ch = 0; ch < N_ROWS / 256; ch++) {
        int4 lv = *(const int4*)(label + ch * 256 + lane * 4);
#pragma unroll
        for (int q = 0; q < 4; q++) {
            int j = ch * 256 + lane * 4 + q;
            bool m = (labof(lv, q) == mylab) && (j != row);
            unsigned long long mask = __ballot(m);
            while (mask) {
                int jj = ch * 256 + 4 * (__ffsll(mask) - 1) + q;
                mask &= mask - 1;
                ushort2 f2 = *(const ushort2*)(enb + (size_t)jj * DIM + lane * 2);
                float d = ei0 * bf2f(f2.x) + ei1 * bf2f(f2.y);
#pragma unroll
                for (int s = 1; s < 64; s <<= 1) d += __shfl_xor(d, s, 64);
                acc += __builtin_amdgcn_exp2f(d);
            }
        }
    }

#pragma unroll
    for (int m = 1; m < 64; m <<= 1) tp += __shfl_xor(tp, m, 64);

    float e = e2p[row];
    float v = __logf((e + acc) / (e + tp));

    __shared__ float red[4];
    if (lane == 0) red[wave] = v;
    __syncthreads();
    if (threadIdx.x == 0) pl[blockIdx.x] = red[0] + red[1] + red[2] + red[3];
}

// Kernel 4: final sum of 2048 partials -> -mean
__global__ __launch_bounds__(256) void loss_final_kernel(
    const float* __restrict__ pl, float* __restrict__ out)
{
    float v = 0.f;
#pragma unroll
    for (int q = 0; q < 8; q++) v += pl[threadIdx.x * 8 + q];
#pragma unroll
    for (int m = 1; m < 64; m <<= 1) v += __shfl_xor(v, m, 64);
    __shared__ float red[4];
    int wave = threadIdx.x >> 6, lane = threadIdx.x & 63;
    if (lane == 0) red[wave] = v;
    __syncthreads();
    if (threadIdx.x == 0)
        out[0] = -(red[0] + red[1] + red[2] + red[3]) / (float)N_ROWS;
}

extern "C" void kernel_launch(void* const* d_in, const int* in_sizes, int n_in,
                              void* d_out, int out_size, void* d_ws, size_t ws_size,
                              hipStream_t stream) {
    const float* embed = (const float*)d_in[0];
    const float* proxy = (const float*)d_in[1];
    const int*   label = (const int*)d_in[2];
    float* out = (float*)d_out;

    char* ws = (char*)d_ws;
    short* enb  = (short*)ws;                                   // 2 MB
    float* e2p  = (float*)(ws + 2u * N_ROWS * DIM);             // 32 KB
    float* ptot = e2p + N_ROWS;                                 // 1 MB
    float* pl   = ptot + NCHUNK * N_ROWS;                       // 8 KB

    hipLaunchKernelGGL(norm_kernel, dim3(N_ROWS / 4), dim3(256), 0, stream,
                       embed, proxy, enb, e2p);
    hipLaunchKernelGGL(simsum_kernel, dim3(N_ROWS / 256, NCHUNK), dim3(256), 0, stream,
                       enb, ptot);
    hipLaunchKernelGGL(posloss_kernel, dim3(N_ROWS / 4), dim3(256), 0, stream,
                       enb, label, e2p, ptot, pl);
    hipLaunchKernelGGL(loss_final_kernel, dim3(1), dim3(256), 0, stream, pl, out);
}

// Round 10
// 76.345 us; speedup vs baseline: 1.3004x; 1.3004x over previous
//
#include <hip/hip_runtime.h>
#include <hip/hip_bf16.h>

#define N_ROWS 8192
#define DIM    128
#define NCHUNK 32                  // column chunks in sim kernel
#define CHUNKC (N_ROWS / NCHUNK)   // 256 cols per chunk
#define NTILE  (CHUNKC / 32)       // 8 tiles of 32 cols per chunk

// sqrt(2*log2(e)) : (s*a)·(s*b) = 2*log2(e)*a·b, so exp2(dot) = exp(2*sim)
#define ENSCALE 1.6986436f

typedef __attribute__((ext_vector_type(8)))  short short8;
typedef __attribute__((ext_vector_type(16))) float f32x16;

__device__ inline unsigned short f2bf(float f) {
    unsigned u = __float_as_uint(f);
    unsigned r = (u + 0x7FFFu + ((u >> 16) & 1u)) >> 16;
    return (unsigned short)r;
}
__device__ inline float bf2f(unsigned short u) {
    return __uint_as_float(((unsigned)u) << 16);
}
__device__ inline int labof(int4 v, int j) {
    return j == 0 ? v.x : j == 1 ? v.y : j == 2 ? v.z : v.w;
}

// Kernel 1: per-row L2 normalize embed -> bf16 (scaled by ENSCALE), and
// e2p[i] = exp(2*dot(en,pn)) in fp32.
__global__ __launch_bounds__(256) void norm_kernel(
    const float* __restrict__ embed, const float* __restrict__ proxy,
    short* __restrict__ enb, float* __restrict__ e2p)
{
    int wave = threadIdx.x >> 6, lane = threadIdx.x & 63;
    int row = blockIdx.x * 4 + wave;

    const float2 ev = *(const float2*)(embed + row * DIM + lane * 2);
    float ss = ev.x * ev.x + ev.y * ev.y;
#pragma unroll
    for (int m = 1; m < 64; m <<= 1) ss += __shfl_xor(ss, m, 64);
    float inv_e = 1.0f / fmaxf(sqrtf(ss), 1e-8f);
    float ex = ev.x * inv_e, ey = ev.y * inv_e;

    const float2 pv = *(const float2*)(proxy + row * DIM + lane * 2);
    float ps = pv.x * pv.x + pv.y * pv.y;
#pragma unroll
    for (int m = 1; m < 64; m <<= 1) ps += __shfl_xor(ps, m, 64);
    float inv_p = 1.0f / fmaxf(sqrtf(ps), 1e-8f);

    float dot = ex * (pv.x * inv_p) + ey * (pv.y * inv_p);
#pragma unroll
    for (int m = 1; m < 64; m <<= 1) dot += __shfl_xor(dot, m, 64);

    ushort2 st; st.x = f2bf(ex * ENSCALE); st.y = f2bf(ey * ENSCALE);
    *(ushort2*)(enb + row * DIM + lane * 2) = st;
    if (lane == 0) e2p[row] = __expf(2.0f * dot);
}

// Kernel 2: fused sim-GEMM + exp + full row sum (tot only; pos separate).
// Direct per-wave B-fragment loads (L2-hit path, R2: FETCH 8.3MB), NO LDS,
// NO barriers. Wave owns 64 rows -> each 8-load tile feeds 16 MFMAs in two
// independent chains. R9 spilled (WRITE 73MB: regs ~146 > 128 cap from
// launch_bounds(256,4)); fix: (256,3) -> cap ~170, 12 waves/CU.
// Operand-swapped MFMA: lane cl owns output rows wrbase+cl / wrbase+32+cl;
// acc regs span tile cols: col(reg) = (reg&3) + 4*hi + 8*(reg>>2).
__global__ __launch_bounds__(256, 3) void simsum_kernel(
    const short* __restrict__ enb, float* __restrict__ ptot)
{
    const int tid = threadIdx.x;
    const int wave = tid >> 6;
    const int lane = tid & 63;
    const int cl = lane & 31;       // output row lane / tile col selector
    const int hi = lane >> 5;       // k-group
    const int wrbase = blockIdx.x * 256 + wave * 64;
    const int cbase0 = blockIdx.y * CHUNKC;

    // register-resident A: the wave's 64 rows, two 32-row groups
    short8 rres0[8], rres1[8];
    {
        const short* a0 = enb + (size_t)(wrbase + cl) * DIM + hi * 8;
        const short* a1 = enb + (size_t)(wrbase + 32 + cl) * DIM + hi * 8;
#pragma unroll
        for (int kk = 0; kk < 8; kk++) {
            rres0[kk] = *(const short8*)(a0 + kk * 16);
            rres1[kk] = *(const short8*)(a1 + kk * 16);
        }
    }

    float tot0[4] = {0.f, 0.f, 0.f, 0.f};
    float tot1[4] = {0.f, 0.f, 0.f, 0.f};

#pragma unroll 2
    for (int t = 0; t < NTILE; t++) {
        const int cb = cbase0 + t * 32;

        // B fragments: lane holds B[k = kk*16 + hi*8 + j][cb + cl]
        const short* brow = enb + (size_t)(cb + cl) * DIM + hi * 8;
        short8 b[8];
#pragma unroll
        for (int kk = 0; kk < 8; kk++)
            b[kk] = *(const short8*)(brow + kk * 16);

        f32x16 c0 = {}, c1 = {};
#pragma unroll
        for (int kk = 0; kk < 8; kk++) {
            c0 = __builtin_amdgcn_mfma_f32_32x32x16_bf16(b[kk], rres0[kk], c0, 0, 0, 0);
            c1 = __builtin_amdgcn_mfma_f32_32x32x16_bf16(b[kk], rres1[kk], c1, 0, 0, 0);
        }

        // wave-uniform branch: only 2 of 8 tiles per wave touch the diagonal
        if (cb == wrbase || cb == wrbase + 32) {
            const bool d0_ = (cb == wrbase);
#pragma unroll
            for (int r = 0; r < 16; r++) {
                int colr = (r & 3) + 4 * hi + 8 * (r >> 2);
                float s0 = __builtin_amdgcn_exp2f(c0[r]);
                float s1 = __builtin_amdgcn_exp2f(c1[r]);
                s0 = (d0_ && colr == cl) ? 0.f : s0;
                s1 = (!d0_ && colr == cl) ? 0.f : s1;
                tot0[r & 3] += s0;
                tot1[r & 3] += s1;
            }
        } else {
#pragma unroll
            for (int r = 0; r < 16; r++) {
                tot0[r & 3] += __builtin_amdgcn_exp2f(c0[r]);
                tot1[r & 3] += __builtin_amdgcn_exp2f(c1[r]);
            }
        }
    }

    float t0 = tot0[0] + tot0[1] + tot0[2] + tot0[3];
    float t1 = tot1[0] + tot1[1] + tot1[2] + tot1[3];
    t0 += __shfl_xor(t0, 32, 64);   // merge the two k-groups (disjoint cols)
    t1 += __shfl_xor(t1, 32, 64);
    if (hi == 0) {
        ptot[blockIdx.y * N_ROWS + wrbase + cl] = t0;
        ptot[blockIdx.y * N_ROWS + wrbase + 32 + cl] = t1;
    }
}

// Kernel 3: positives + per-row loss, fused. One wave per row: int4
// ballot-scan labels, lane-parallel dot per same-label j, accumulate
// exp2; then the row's log-ratio (ptot partials read LANE-PARALLEL);
// block partial (4 rows) -> pl.
__global__ __launch_bounds__(256) void posloss_kernel(
    const short* __restrict__ enb, const int* __restrict__ label,
    const float* __restrict__ e2p, const float* __restrict__ ptot,
    float* __restrict__ pl)
{
    int wave = threadIdx.x >> 6, lane = threadIdx.x & 63;
    int row = blockIdx.x * 4 + wave;
    int mylab = label[row];

    ushort2 e2 = *(const ushort2*)(enb + (size_t)row * DIM + lane * 2);
    float ei0 = bf2f(e2.x), ei1 = bf2f(e2.y);

    // parallel partial-sum read (32 lanes, one per chunk)
    float tp = (lane < NCHUNK) ? ptot[lane * N_ROWS + row] : 0.f;

    float acc = 0.f;
#pragma unroll 1
    for (int ch = 0; ch < N_ROWS / 256; ch++) {
        int4 lv = *(const int4*)(label + ch * 256 + lane * 4);
#pragma unroll
        for (int q = 0; q < 4; q++) {
            int j = ch * 256 + lane * 4 + q;
            bool m = (labof(lv, q) == mylab) && (j != row);
            unsigned long long mask = __ballot(m);
            while (mask) {
                int jj = ch * 256 + 4 * (__ffsll(mask) - 1) + q;
                mask &= mask - 1;
                ushort2 f2 = *(const ushort2*)(enb + (size_t)jj * DIM + lane * 2);
                float d = ei0 * bf2f(f2.x) + ei1 * bf2f(f2.y);
#pragma unroll
                for (int s = 1; s < 64; s <<= 1) d += __shfl_xor(d, s, 64);
                acc += __builtin_amdgcn_exp2f(d);
            }
        }
    }

#pragma unroll
    for (int m = 1; m < 64; m <<= 1) tp += __shfl_xor(tp, m, 64);

    float e = e2p[row];
    float v = __logf((e + acc) / (e + tp));

    __shared__ float red[4];
    if (lane == 0) red[wave] = v;
    __syncthreads();
    if (threadIdx.x == 0) pl[blockIdx.x] = red[0] + red[1] + red[2] + red[3];
}

// Kernel 4: final sum of 2048 partials -> -mean
__global__ __launch_bounds__(256) void loss_final_kernel(
    const float* __restrict__ pl, float* __restrict__ out)
{
    float v = 0.f;
#pragma unroll
    for (int q = 0; q < 8; q++) v += pl[threadIdx.x * 8 + q];
#pragma unroll
    for (int m = 1; m < 64; m <<= 1) v += __shfl_xor(v, m, 64);
    __shared__ float red[4];
    int wave = threadIdx.x >> 6, lane = threadIdx.x & 63;
    if (lane == 0) red[wave] = v;
    __syncthreads();
    if (threadIdx.x == 0)
        out[0] = -(red[0] + red[1] + red[2] + red[3]) / (float)N_ROWS;
}

extern "C" void kernel_launch(void* const* d_in, const int* in_sizes, int n_in,
                              void* d_out, int out_size, void* d_ws, size_t ws_size,
                              hipStream_t stream) {
    const float* embed = (const float*)d_in[0];
    const float* proxy = (const float*)d_in[1];
    const int*   label = (const int*)d_in[2];
    float* out = (float*)d_out;

    char* ws = (char*)d_ws;
    short* enb  = (short*)ws;                                   // 2 MB
    float* e2p  = (float*)(ws + 2u * N_ROWS * DIM);             // 32 KB
    float* ptot = e2p + N_ROWS;                                 // 1 MB
    float* pl   = ptot + NCHUNK * N_ROWS;                       // 8 KB

    hipLaunchKernelGGL(norm_kernel, dim3(N_ROWS / 4), dim3(256), 0, stream,
                       embed, proxy, enb, e2p);
    hipLaunchKernelGGL(simsum_kernel, dim3(N_ROWS / 256, NCHUNK), dim3(256), 0, stream,
                       enb, ptot);
    hipLaunchKernelGGL(posloss_kernel, dim3(N_ROWS / 4), dim3(256), 0, stream,
                       enb, label, e2p, ptot, pl);
    hipLaunchKernelGGL(loss_final_kernel, dim3(1), dim3(256), 0, stream, pl, out);
}

// Round 11
// 55.679 us; speedup vs baseline: 1.7831x; 1.3712x over previous
//
#include <hip/hip_runtime.h>
#include <hip/hip_bf16.h>

#define N_ROWS 8192
#define DIM    128
#define NCHUNK 16                  // column chunks in sim kernel
#define CHUNKC (N_ROWS / NCHUNK)   // 512 cols per chunk
#define NTILE  (CHUNKC / 32)       // 16 tiles of 32 cols per chunk

// sqrt(2*log2(e)) : (s*a)·(s*b) = 2*log2(e)*a·b, so exp2(dot) = exp(2*sim)
#define ENSCALE 1.6986436f

typedef __attribute__((ext_vector_type(8)))  short short8;
typedef __attribute__((ext_vector_type(16))) float f32x16;

__device__ inline unsigned short f2bf(float f) {
    unsigned u = __float_as_uint(f);
    unsigned r = (u + 0x7FFFu + ((u >> 16) & 1u)) >> 16;
    return (unsigned short)r;
}
__device__ inline float bf2f(unsigned short u) {
    return __uint_as_float(((unsigned)u) << 16);
}
__device__ inline int labof(int4 v, int j) {
    return j == 0 ? v.x : j == 1 ? v.y : j == 2 ? v.z : v.w;
}

// Kernel 1: per-row L2 normalize embed -> bf16 (scaled by ENSCALE), and
// e2p[i] = exp(2*dot(en,pn)) in fp32.
__global__ __launch_bounds__(256) void norm_kernel(
    const float* __restrict__ embed, const float* __restrict__ proxy,
    short* __restrict__ enb, float* __restrict__ e2p)
{
    int wave = threadIdx.x >> 6, lane = threadIdx.x & 63;
    int row = blockIdx.x * 4 + wave;

    const float2 ev = *(const float2*)(embed + row * DIM + lane * 2);
    float ss = ev.x * ev.x + ev.y * ev.y;
#pragma unroll
    for (int m = 1; m < 64; m <<= 1) ss += __shfl_xor(ss, m, 64);
    float inv_e = 1.0f / fmaxf(sqrtf(ss), 1e-8f);
    float ex = ev.x * inv_e, ey = ev.y * inv_e;

    const float2 pv = *(const float2*)(proxy + row * DIM + lane * 2);
    float ps = pv.x * pv.x + pv.y * pv.y;
#pragma unroll
    for (int m = 1; m < 64; m <<= 1) ps += __shfl_xor(ps, m, 64);
    float inv_p = 1.0f / fmaxf(sqrtf(ps), 1e-8f);

    float dot = ex * (pv.x * inv_p) + ey * (pv.y * inv_p);
#pragma unroll
    for (int m = 1; m < 64; m <<= 1) dot += __shfl_xor(dot, m, 64);

    ushort2 st; st.x = f2bf(ex * ENSCALE); st.y = f2bf(ey * ENSCALE);
    *(ushort2*)(enb + row * DIM + lane * 2) = st;
    if (lane == 0) e2p[row] = __expf(2.0f * dot);
}

// Kernel 2: fused sim-GEMM + exp + full row sum (tot only; pos separate).
// R10 diagnosis: direct fragment loads are 32-line gathers; 4 waves x 8
// loads per tile = 1024 line-transactions per block-tile -> TA-throughput
// bound (48us, MfmaUtil 12%). Fix: gather ONCE per block (wave w loads only
// fragments kk=2w,2w+1 -> 256 line-transactions/block-tile, keeping the
// scattered 16B pattern that demonstrably allocates in L2, FETCH 8.2MB),
// share via LDS in FRAGMENT layout (lane-linear 16B, bank-optimal, no
// swizzle). One __syncthreads per tile; next tile's gather issues right
// after the barrier and is covered by the current tile's compute.
// Operand-swapped MFMA: lane cl owns output rows wrbase+cl / wrbase+32+cl;
// acc regs span tile cols: col(reg) = (reg&3) + 4*hi + 8*(reg>>2).
__global__ __launch_bounds__(256, 2) void simsum_kernel(
    const short* __restrict__ enb, float* __restrict__ ptot)
{
    __shared__ __align__(16) char lds[2 * 8192];
    const int tid = threadIdx.x;
    const int wave = tid >> 6;
    const int lane = tid & 63;
    const int cl = lane & 31;       // output row lane / tile col selector
    const int hi = lane >> 5;       // k-group
    const int wrbase = blockIdx.x * 256 + wave * 64;
    const int cbase0 = blockIdx.y * CHUNKC;

    // register-resident A: the wave's 64 rows, two 32-row groups
    short8 rres0[8], rres1[8];
    {
        const short* a0 = enb + (size_t)(wrbase + cl) * DIM + hi * 8;
        const short* a1 = enb + (size_t)(wrbase + 32 + cl) * DIM + hi * 8;
#pragma unroll
        for (int kk = 0; kk < 8; kk++) {
            rres0[kk] = *(const short8*)(a0 + kk * 16);
            rres1[kk] = *(const short8*)(a1 + kk * 16);
        }
    }

    float tot0[4] = {0.f, 0.f, 0.f, 0.f};
    float tot1[4] = {0.f, 0.f, 0.f, 0.f};

    // this wave's two gather fragments: kk0 = 2*wave, kk1 = 2*wave+1
    short8 g0, g1;
#define GLOAD(t)                                                               \
    {                                                                          \
        const short* brow_ =                                                   \
            enb + (size_t)(cbase0 + (t) * 32 + cl) * DIM + hi * 8;             \
        g0 = *(const short8*)(brow_ + (2 * wave) * 16);                        \
        g1 = *(const short8*)(brow_ + (2 * wave + 1) * 16);                    \
    }

    GLOAD(0);

#pragma unroll 1
    for (int t = 0; t < NTILE; t++) {
        const int buf = (t & 1) * 8192;
        // stage this wave's fragments (fragment layout: kk*1024 + lane*16)
        *(short8*)(lds + buf + wave * 2048 + lane * 16) = g0;
        *(short8*)(lds + buf + wave * 2048 + 1024 + lane * 16) = g1;
        __syncthreads();           // buf visible; nothing else in flight
        if (t + 1 < NTILE) GLOAD(t + 1);   // in flight across compute

        short8 b[8];
#pragma unroll
        for (int kk = 0; kk < 8; kk++)
            b[kk] = *(const short8*)(lds + buf + kk * 1024 + lane * 16);

        f32x16 c0 = {}, c1 = {};
        __builtin_amdgcn_s_setprio(1);
#pragma unroll
        for (int kk = 0; kk < 8; kk++) {
            c0 = __builtin_amdgcn_mfma_f32_32x32x16_bf16(b[kk], rres0[kk], c0, 0, 0, 0);
            c1 = __builtin_amdgcn_mfma_f32_32x32x16_bf16(b[kk], rres1[kk], c1, 0, 0, 0);
        }
        __builtin_amdgcn_s_setprio(0);

        const int cb = cbase0 + t * 32;
        // wave-uniform branch: only 2 of 16 tiles per wave touch the diagonal
        if (cb == wrbase || cb == wrbase + 32) {
            const bool d0_ = (cb == wrbase);
#pragma unroll
            for (int r = 0; r < 16; r++) {
                int colr = (r & 3) + 4 * hi + 8 * (r >> 2);
                float s0 = __builtin_amdgcn_exp2f(c0[r]);
                float s1 = __builtin_amdgcn_exp2f(c1[r]);
                s0 = (d0_ && colr == cl) ? 0.f : s0;
                s1 = (!d0_ && colr == cl) ? 0.f : s1;
                tot0[r & 3] += s0;
                tot1[r & 3] += s1;
            }
        } else {
#pragma unroll
            for (int r = 0; r < 16; r++) {
                tot0[r & 3] += __builtin_amdgcn_exp2f(c0[r]);
                tot1[r & 3] += __builtin_amdgcn_exp2f(c1[r]);
            }
        }
    }
#undef GLOAD

    float t0 = tot0[0] + tot0[1] + tot0[2] + tot0[3];
    float t1 = tot1[0] + tot1[1] + tot1[2] + tot1[3];
    t0 += __shfl_xor(t0, 32, 64);   // merge the two k-groups (disjoint cols)
    t1 += __shfl_xor(t1, 32, 64);
    if (hi == 0) {
        ptot[blockIdx.y * N_ROWS + wrbase + cl] = t0;
        ptot[blockIdx.y * N_ROWS + wrbase + 32 + cl] = t1;
    }
}

// Kernel 3: positives + per-row loss, fused. One wave per row: int4
// ballot-scan labels, lane-parallel dot per same-label j, accumulate
// exp2; then the row's log-ratio (ptot partials read LANE-PARALLEL);
// block partial (4 rows) -> pl.
__global__ __launch_bounds__(256) void posloss_kernel(
    const short* __restrict__ enb, const int* __restrict__ label,
    const float* __restrict__ e2p, const float* __restrict__ ptot,
    float* __restrict__ pl)
{
    int wave = threadIdx.x >> 6, lane = threadIdx.x & 63;
    int row = blockIdx.x * 4 + wave;
    int mylab = label[row];

    ushort2 e2 = *(const ushort2*)(enb + (size_t)row * DIM + lane * 2);
    float ei0 = bf2f(e2.x), ei1 = bf2f(e2.y);

    // parallel partial-sum read (16 lanes, one per chunk)
    float tp = (lane < NCHUNK) ? ptot[lane * N_ROWS + row] : 0.f;

    float acc = 0.f;
#pragma unroll 1
    for (int ch = 0; ch < N_ROWS / 256; ch++) {
        int4 lv = *(const int4*)(label + ch * 256 + lane * 4);
#pragma unroll
        for (int q = 0; q < 4; q++) {
            int j = ch * 256 + lane * 4 + q;
            bool m = (labof(lv, q) == mylab) && (j != row);
            unsigned long long mask = __ballot(m);
            while (mask) {
                int jj = ch * 256 + 4 * (__ffsll(mask) - 1) + q;
                mask &= mask - 1;
                ushort2 f2 = *(const ushort2*)(enb + (size_t)jj * DIM + lane * 2);
                float d = ei0 * bf2f(f2.x) + ei1 * bf2f(f2.y);
#pragma unroll
                for (int s = 1; s < 64; s <<= 1) d += __shfl_xor(d, s, 64);
                acc += __builtin_amdgcn_exp2f(d);
            }
        }
    }

#pragma unroll
    for (int m = 1; m < 64; m <<= 1) tp += __shfl_xor(tp, m, 64);

    float e = e2p[row];
    float v = __logf((e + acc) / (e + tp));

    __shared__ float red[4];
    if (lane == 0) red[wave] = v;
    __syncthreads();
    if (threadIdx.x == 0) pl[blockIdx.x] = red[0] + red[1] + red[2] + red[3];
}

// Kernel 4: final sum of 2048 partials -> -mean
__global__ __launch_bounds__(256) void loss_final_kernel(
    const float* __restrict__ pl, float* __restrict__ out)
{
    float v = 0.f;
#pragma unroll
    for (int q = 0; q < 8; q++) v += pl[threadIdx.x * 8 + q];
#pragma unroll
    for (int m = 1; m < 64; m <<= 1) v += __shfl_xor(v, m, 64);
    __shared__ float red[4];
    int wave = threadIdx.x >> 6, lane = threadIdx.x & 63;
    if (lane == 0) red[wave] = v;
    __syncthreads();
    if (threadIdx.x == 0)
        out[0] = -(red[0] + red[1] + red[2] + red[3]) / (float)N_ROWS;
}

extern "C" void kernel_launch(void* const* d_in, const int* in_sizes, int n_in,
                              void* d_out, int out_size, void* d_ws, size_t ws_size,
                              hipStream_t stream) {
    const float* embed = (const float*)d_in[0];
    const float* proxy = (const float*)d_in[1];
    const int*   label = (const int*)d_in[2];
    float* out = (float*)d_out;

    char* ws = (char*)d_ws;
    short* enb  = (short*)ws;                                   // 2 MB
    float* e2p  = (float*)(ws + 2u * N_ROWS * DIM);             // 32 KB
    float* ptot = e2p + N_ROWS;                                 // 512 KB
    float* pl   = ptot + NCHUNK * N_ROWS;                       // 8 KB

    hipLaunchKernelGGL(norm_kernel, dim3(N_ROWS / 4), dim3(256), 0, stream,
                       embed, proxy, enb, e2p);
    hipLaunchKernelGGL(simsum_kernel, dim3(N_ROWS / 256, NCHUNK), dim3(256), 0, stream,
                       enb, ptot);
    hipLaunchKernelGGL(posloss_kernel, dim3(N_ROWS / 4), dim3(256), 0, stream,
                       enb, label, e2p, ptot, pl);
    hipLaunchKernelGGL(loss_final_kernel, dim3(1), dim3(256), 0, stream, pl, out);
}